// Round 4
// baseline (64.611 us; speedup 1.0000x reference)
//
#include <hip/hip_runtime.h>

#define K_OFF 27
#define CIN   2
#define COUT  16
#define BLK   256
#define WAVES 4
#define IPW   (64 * K_OFF)   // ints per wave-tile = 1728
#define I4PW  (IPW / 4)      // 432 int4 per wave-tile

__global__ __launch_bounds__(BLK) void spconv_kernel(
    const float* __restrict__ feats,   // [N][2]
    const float* __restrict__ w,       // [27][2][16]
    const int*   __restrict__ nbr,     // [N][27]
    float*       __restrict__ out,     // [N][16]
    int n_pts, int n_tiles)
{
    __shared__ int s_nbr[WAVES * IPW];          // 27648 B, wave-partitioned

    const int tid  = threadIdx.x;
    const int lane = tid & 63;
    const int wv   = tid >> 6;
    int* sw = s_nbr + wv * IPW;                 // wave-private 6912 B
    int4* sw4 = reinterpret_cast<int4*>(sw);

    const long long total_ints = (long long)n_pts * K_OFF;
    const float2* feats2 = reinterpret_cast<const float2*>(feats);

    const int wstride = gridDim.x * WAVES;
    int tile = blockIdx.x * WAVES + wv;
    if (tile >= n_tiles) return;

    // ---- prologue: stage tile0's nbr rows into registers (coalesced int4) ----
    int4 r[7];
    {
        const long long g0 = (long long)tile * IPW;
        const int4* g4 = reinterpret_cast<const int4*>(nbr + g0);
        #pragma unroll
        for (int j = 0; j < 7; ++j) {
            const int i = lane + j * 64;
            const long long g = g0 + (long long)i * 4;
            r[j] = (i < I4PW && g + 3 < total_ints) ? g4[i] : make_int4(-1,-1,-1,-1);
        }
    }

    while (true) {
        // ---- write staged regs -> wave-private LDS (write-late) ----
        #pragma unroll
        for (int j = 0; j < 7; ++j) {
            const int i = lane + j * 64;
            if (i < I4PW) sw4[i] = r[j];
        }
        asm volatile("s_waitcnt lgkmcnt(0)" ::: "memory");
        __builtin_amdgcn_sched_barrier(0);
        __builtin_amdgcn_wave_barrier();

        const int cur = tile;
        tile += wstride;
        const bool more = (tile < n_tiles);

        // ---- issue-early: next tile's stage loads, in flight during compute ----
        if (more) {
            const long long g0 = (long long)tile * IPW;
            const int4* g4 = reinterpret_cast<const int4*>(nbr + g0);
            #pragma unroll
            for (int j = 0; j < 7; ++j) {
                const int i = lane + j * 64;
                const long long g = g0 + (long long)i * 4;
                r[j] = (i < I4PW && g + 3 < total_ints) ? g4[i] : make_int4(-1,-1,-1,-1);
            }
        }

        // ---- compute tile `cur` from LDS: 14 + 13 gather batches ----
        float acc[COUT];
        #pragma unroll
        for (int d = 0; d < COUT; ++d) acc[d] = 0.f;
        const int row = lane * K_OFF;

        {
            float2 f[14]; float m[14];
            #pragma unroll
            for (int j = 0; j < 14; ++j) {
                const int idx = sw[row + j];          // stride-27: conflict-free
                m[j] = (idx >= 0) ? 1.0f : 0.0f;
                f[j] = feats2[idx > 0 ? idx : 0];     // invalid lanes broadcast line 0
            }
            #pragma unroll
            for (int j = 0; j < 14; ++j) {
                const float fx = f[j].x * m[j];
                const float fy = f[j].y * m[j];
                const float* wk = w + j * (CIN * COUT);   // uniform -> s_load
                #pragma unroll
                for (int d = 0; d < COUT; ++d) {
                    acc[d] = fmaf(fx, wk[d],        acc[d]);
                    acc[d] = fmaf(fy, wk[COUT + d], acc[d]);
                }
            }
        }
        {
            float2 f[13]; float m[13];
            #pragma unroll
            for (int j = 0; j < 13; ++j) {
                const int idx = sw[row + 14 + j];
                m[j] = (idx >= 0) ? 1.0f : 0.0f;
                f[j] = feats2[idx > 0 ? idx : 0];
            }
            #pragma unroll
            for (int j = 0; j < 13; ++j) {
                const float fx = f[j].x * m[j];
                const float fy = f[j].y * m[j];
                const float* wk = w + (14 + j) * (CIN * COUT);
                #pragma unroll
                for (int d = 0; d < COUT; ++d) {
                    acc[d] = fmaf(fx, wk[d],        acc[d]);
                    acc[d] = fmaf(fy, wk[COUT + d], acc[d]);
                }
            }
        }

        // ---- store 64B/thread coalesced ----
        const int n = cur * 64 + lane;
        if (n < n_pts) {
            float4* o = reinterpret_cast<float4*>(out + (size_t)n * COUT);
            o[0] = make_float4(acc[0],  acc[1],  acc[2],  acc[3]);
            o[1] = make_float4(acc[4],  acc[5],  acc[6],  acc[7]);
            o[2] = make_float4(acc[8],  acc[9],  acc[10], acc[11]);
            o[3] = make_float4(acc[12], acc[13], acc[14], acc[15]);
        }

        if (!more) break;
        // drain this tile's ds_reads before overwriting the buffer next iter
        asm volatile("s_waitcnt lgkmcnt(0)" ::: "memory");
        __builtin_amdgcn_wave_barrier();
    }
}

extern "C" void kernel_launch(void* const* d_in, const int* in_sizes, int n_in,
                              void* d_out, int out_size, void* d_ws, size_t ws_size,
                              hipStream_t stream) {
    const float* feats = (const float*)d_in[0];
    const float* w     = (const float*)d_in[1];
    const int*   nbr   = (const int*)d_in[2];
    float*       out   = (float*)d_out;

    const int n_pts   = in_sizes[0] / CIN;
    const int n_tiles = (n_pts + 63) / 64;
    int grid = (n_tiles + WAVES - 1) / WAVES;
    if (grid > 1280) grid = 1280;              // ~5 blocks/CU, grid-stride pipeline

    spconv_kernel<<<grid, BLK, 0, stream>>>(feats, w, nbr, out, n_pts, n_tiles);
}